// Round 8
// baseline (190.829 us; speedup 1.0000x reference)
//
#include <hip/hip_runtime.h>
#include <hip/hip_bf16.h>
#include <cstdint>
#include <cstddef>

#define C_CH 128
#define L_LEN 16384
#define B_N 8
#define K_T 3
#define EPS 1e-5f
#define WPADL 8
#define WIN 144   // staged rows: l = l0-8 .. l0+135 (verified R5/R6 window)

typedef __attribute__((ext_vector_type(8))) short short8;
typedef __attribute__((ext_vector_type(4))) float float4v;

__device__ __forceinline__ short f2bf(float f) {
  union { float f; unsigned u; } v; v.f = f;
  unsigned r = v.u + 0x7fffu + ((v.u >> 16) & 1u);
  return (short)(r >> 16);
}
__device__ __forceinline__ float bflo(unsigned d) {
  union { unsigned u; float f; } v; v.u = d << 16; return v.f;
}
__device__ __forceinline__ float bfhi(unsigned d) {
  union { unsigned u; float f; } v; v.u = d & 0xffff0000u; return v.f;
}
__device__ __forceinline__ unsigned packbf(float a, float b) {
  unsigned ua = __float_as_uint(a) + 0x8000u;
  unsigned ub = __float_as_uint(b) + 0x8000u;
  return (ua >> 16) | (ub & 0xffff0000u);
}
__device__ __forceinline__ int clampL(int v) {
  return v < 0 ? 0 : (v > L_LEN - 1 ? L_LEN - 1 : v);
}

// ---- repack dc_w [m][c][kt] f32 -> Wp2 bf16, linear = ((ks*4+qk)*128 + m)*8 + j,
// A[m][k=ks*32+qk*8+j] = dcw[m][c][kt], c = qk*32 + (ks&3)*8 + j, kt = ks>>2.
__global__ void repack_w2(const float* __restrict__ dc_w, short* __restrict__ Wp2) {
  int tid = blockIdx.x * 256 + threadIdx.x;
  if (tid >= C_CH * C_CH * K_T) return;
  int j = tid & 7;
  int m = (tid >> 3) & 127;
  int qk = (tid >> 10) & 3;
  int ks = tid >> 12;
  int kt = ks >> 2, s = ks & 3;
  int c = qk * 32 + s * 8 + j;
  Wp2[tid] = f2bf(dc_w[(m * C_CH + c) * K_T + kt]);
}

// ---- Fused kernel. R6 structure verbatim in phases A and B; changes limited to:
//  (1) exchange packed as uint2{wab, r01} -> full-128B-line stores, halved loads;
//  (2) LDS-transpose epilogue: acc -> xs (reused, f32, ^qk chunk swizzle) ->
//      float4 full-line out stores (two 64-row halves).
// LDS = 36,864 (xs) + 4,096 (swt) = 40,960 B exactly -> 4 blocks/CU.
__global__ __launch_bounds__(256, 4) void fused_deform(
    const float* __restrict__ x,
    const float* __restrict__ dw_w, const float* __restrict__ dw_b,
    const float* __restrict__ ln_g, const float* __restrict__ ln_b,
    const float* __restrict__ off_w, const float* __restrict__ off_b,
    const short* __restrict__ Wp2,
    uint2* __restrict__ g_pk,
    float* __restrict__ out) {
  __shared__ short xs[WIN * 128];   // 36,864 B (reused as f32 tile in epilogue)
  __shared__ float swt[1024];       // 4,096 B: dw_w[384] dw_b[128] ln_gb_packed[128] off_w[384]

  int t = threadIdx.x;
  int b = blockIdx.y;
  int l0 = blockIdx.x * 128;
  int wb0 = l0 - WPADL;
  const float* xb = x + (size_t)b * C_CH * L_LEN;
  char* xsb = (char*)xs;

  for (int i = t; i < 1024; i += 256) {
    float v;
    if (i < 384) v = dw_w[i];
    else if (i < 512) v = dw_b[i - 384];
    else if (i < 640) v = __uint_as_float(packbf(ln_g[i - 512], ln_b[i - 512]));
    else v = off_w[i - 640];
    swt[i] = v;
  }

  int lane = t & 63, wv = t >> 6;

  // ---- phase A (verbatim R6): stage x -> LDS bf16, XOR-16 swizzled rows.
  {
    int cc = wv * 4 + (lane >> 4);    // chunk 0..15
    int lqi = lane & 15;
    #pragma unroll
    for (int i = 0; i < 3; ++i) {
      int lq = i * 16 + lqi;          // quad-row task; 36*4 = 144 rows exact
      if (lq < 36) {
        int bl = wb0 + lq * 4;
        float fv[8][4];
        if (bl >= 0 && bl + 3 <= L_LEN - 1) {
          #pragma unroll
          for (int j = 0; j < 8; ++j) {
            float4 f = *(const float4*)(xb + (size_t)(cc * 8 + j) * L_LEN + bl);
            fv[j][0] = f.x; fv[j][1] = f.y; fv[j][2] = f.z; fv[j][3] = f.w;
          }
        } else {
          #pragma unroll
          for (int j = 0; j < 8; ++j)
            #pragma unroll
            for (int k = 0; k < 4; ++k)
              fv[j][k] = xb[(size_t)(cc * 8 + j) * L_LEN + clampL(bl + k)];
        }
        #pragma unroll
        for (int k = 0; k < 4; ++k) {
          int rr = lq * 4 + k;
          uint4 q;
          q.x = packbf(fv[0][k], fv[1][k]);
          q.y = packbf(fv[2][k], fv[3][k]);
          q.z = packbf(fv[4][k], fv[5][k]);
          q.w = packbf(fv[6][k], fv[7][k]);
          *(uint4*)(xsb + rr * 256 + ((cc ^ (rr & 15)) << 4)) = q;
        }
      }
    }
  }
  __syncthreads();   // covers swt + xs staging

  // ---- phase B (verbatim R6 producer): dwconv + LN + ReLU + offset linear,
  // post-reject (wab, r01) written packed to the block-private global slice.
  #pragma unroll
  for (int it = 0; it < 2; ++it) {
    int l_loc = (t >> 2) + it * 64;
    int sub = t & 3;
    int lg = l0 + l_loc;
    float mL = (lg >= 1) ? 1.f : 0.f;
    float mR = (lg + 1 < L_LEN) ? 1.f : 0.f;
    int rm = l_loc + WPADL;

    float ys[32];
    float sum = 0.f, sumsq = 0.f;
    #pragma unroll
    for (int oct = 0; oct < 4; ++oct) {
      int ch = sub * 4 + oct;
      int r0 = rm - 1, r1 = rm, r2 = rm + 1;
      uint4 q0 = *(const uint4*)(xsb + r0 * 256 + ((ch ^ (r0 & 15)) << 4));
      uint4 q1 = *(const uint4*)(xsb + r1 * 256 + ((ch ^ (r1 & 15)) << 4));
      uint4 q2 = *(const uint4*)(xsb + r2 * 256 + ((ch ^ (r2 & 15)) << 4));
      const unsigned* u0 = (const unsigned*)&q0;
      const unsigned* u1 = (const unsigned*)&q1;
      const unsigned* u2 = (const unsigned*)&q2;
      #pragma unroll
      for (int j = 0; j < 4; ++j) {
        int c = ch * 8 + 2 * j;
        float y0 = swt[384 + c] + mL * bflo(u0[j]) * swt[3 * c]
                 + bflo(u1[j]) * swt[3 * c + 1] + mR * bflo(u2[j]) * swt[3 * c + 2];
        float y1 = swt[385 + c] + mL * bfhi(u0[j]) * swt[3 * c + 3]
                 + bfhi(u1[j]) * swt[3 * c + 4] + mR * bfhi(u2[j]) * swt[3 * c + 5];
        ys[oct * 8 + 2 * j] = y0;
        ys[oct * 8 + 2 * j + 1] = y1;
        sum += y0 + y1;
        sumsq += y0 * y0 + y1 * y1;
      }
    }
    sum += __shfl_xor(sum, 1, 64);     sum += __shfl_xor(sum, 2, 64);
    sumsq += __shfl_xor(sumsq, 1, 64); sumsq += __shfl_xor(sumsq, 2, 64);
    float mean = sum * (1.f / C_CH);
    float var = sumsq * (1.f / C_CH) - mean * mean;
    float rstd = rsqrtf(var + EPS);

    float o0 = 0.f, o1 = 0.f, o2 = 0.f;
    const unsigned* lngb = (const unsigned*)swt;
    #pragma unroll
    for (int li = 0; li < 32; ++li) {
      int c = sub * 32 + li;
      unsigned gb = lngb[512 + c];
      float yn = (ys[li] - mean) * rstd * bflo(gb) + bfhi(gb);
      float yr = yn > 0.f ? yn : 0.f;
      o0 += yr * swt[640 + c];
      o1 += yr * swt[768 + c];
      o2 += yr * swt[896 + c];
    }
    o0 += __shfl_xor(o0, 1, 64); o0 += __shfl_xor(o0, 2, 64);
    o1 += __shfl_xor(o1, 1, 64); o1 += __shfl_xor(o1, 2, 64);
    o2 += __shfl_xor(o2, 1, 64); o2 += __shfl_xor(o2, 2, 64);

    if (sub < 3) {
      float o = (sub == 0 ? o0 : (sub == 1 ? o1 : o2)) + off_b[sub];
      float pos = (float)(lg + sub - 1) + o;
      float p0f = floorf(pos);
      float fr = pos - p0f;
      int i0 = (int)p0f, i1 = i0 + 1;
      float wa = (i0 >= 0 && i0 < L_LEN) ? (1.f - fr) : 0.f;
      float wbv = (i1 >= 0 && i1 < L_LEN) ? fr : 0.f;
      int i0c = clampL(i0), i1c = clampL(i1);
      unsigned wab = packbf(wa, wbv);
      int r0 = i0c - wb0;
      int r1 = i1c - wb0;
      if ((unsigned)r0 >= WIN) { r0 = 0; wab &= 0xffff0000u; }
      if ((unsigned)r1 >= WIN) { r1 = 0; wab &= 0x0000ffffu; }
      size_t di = ((size_t)b * K_T + sub) * L_LEN + lg;
      g_pk[di] = make_uint2(wab, (unsigned)r0 | ((unsigned)r1 << 16));
    }
  }
  __syncthreads();   // drains global stores (vmcnt(0) before s_barrier);
                     // block-private slice, same CU/L2 -> loads below are L2-hits

  // ---- phase C (verbatim R6 consumer, packed exchange loads)
  int qk = lane >> 4, hrow = lane & 15;

  unsigned c_wab[K_T][2], c_r01[K_T][2];
  {
    const uint2* gp = g_pk + (size_t)b * K_T * L_LEN + l0;
    #pragma unroll
    for (int kt = 0; kt < 3; ++kt) {
      #pragma unroll
      for (int nt = 0; nt < 2; ++nt) {
        int n = wv * 32 + nt * 16 + hrow;
        uint2 w = gp[(size_t)kt * L_LEN + n];
        c_wab[kt][nt] = w.x;
        c_r01[kt][nt] = w.y;
      }
    }
  }

  float4v acc[8][2];
  #pragma unroll
  for (int i = 0; i < 8; ++i) {
    acc[i][0] = (float4v){0.f, 0.f, 0.f, 0.f};
    acc[i][1] = (float4v){0.f, 0.f, 0.f, 0.f};
  }
  const short* wpb = Wp2 + qk * 1024 + hrow * 8;

  #pragma unroll
  for (int kt = 0; kt < 3; ++kt) {
    float wa[2], wbv[2];
    int b0[2], m0_[2], b1[2], m1_[2];
    #pragma unroll
    for (int nt = 0; nt < 2; ++nt) {
      unsigned wab = c_wab[kt][nt];
      wa[nt] = bflo(wab);
      wbv[nt] = bfhi(wab);
      unsigned r01 = c_r01[kt][nt];
      int r0 = r01 & 0xffff, r1 = r01 >> 16;
      b0[nt] = r0 * 256; m0_[nt] = r0 & 15;
      b1[nt] = r1 * 256; m1_[nt] = r1 & 15;
    }
    #pragma unroll
    for (int s = 0; s < 4; ++s) {
      int ks = kt * 4 + s;
      int ch = qk * 4 + s;
      short8 bfrag[2];
      #pragma unroll
      for (int nt = 0; nt < 2; ++nt) {
        uint4 q0 = *(const uint4*)(xsb + b0[nt] + ((ch ^ m0_[nt]) << 4));
        uint4 q1 = *(const uint4*)(xsb + b1[nt] + ((ch ^ m1_[nt]) << 4));
        const unsigned* q0u = (const unsigned*)&q0;
        const unsigned* q1u = (const unsigned*)&q1;
        union { unsigned u[4]; short8 s8; } bu;
        #pragma unroll
        for (int j = 0; j < 4; ++j) {
          float glo = wa[nt] * bflo(q0u[j]) + wbv[nt] * bflo(q1u[j]);
          float ghi = wa[nt] * bfhi(q0u[j]) + wbv[nt] * bfhi(q1u[j]);
          bu.u[j] = packbf(glo, ghi);
        }
        bfrag[nt] = bu.s8;
      }
      const short* wk = wpb + ks * 4096;
      #pragma unroll
      for (int mt = 0; mt < 8; ++mt) {
        short8 a = *(const short8*)(wk + mt * 128);
        acc[mt][0] = __builtin_amdgcn_mfma_f32_16x16x32_bf16(a, bfrag[0], acc[mt][0], 0, 0, 0);
        acc[mt][1] = __builtin_amdgcn_mfma_f32_16x16x32_bf16(a, bfrag[1], acc[mt][1], 0, 0, 0);
      }
    }
  }

  // ---- epilogue: acc -> LDS (xs reused as f32, ^qk chunk swizzle) -> coalesced
  // float4 out stores. Two halves of 64 M-rows (32 KB each <= 36,864 B).
  float* fs = (float*)xs;
  float* ob = out + (size_t)b * C_CH * L_LEN + l0;
  #pragma unroll
  for (int h = 0; h < 2; ++h) {
    __syncthreads();   // xs/fs free (kt loop or previous half's reads done)
    #pragma unroll
    for (int mi = 0; mi < 4; ++mi) {
      int mt = h * 4 + mi;
      #pragma unroll
      for (int nt = 0; nt < 2; ++nt) {
        int col = wv * 32 + nt * 16 + hrow;
        int c4 = col >> 2, cl = col & 3;
        int pc4 = c4 ^ qk;               // chunk swizzle: spreads 4 qk groups
        #pragma unroll
        for (int r = 0; r < 4; ++r) {
          int row = mi * 16 + qk * 4 + r;   // 0..63; (row>>2)&3 == qk
          fs[row * 128 + (pc4 << 2) + cl] = acc[mt][nt][r];
        }
      }
    }
    __syncthreads();
    #pragma unroll
    for (int i = 0; i < 8; ++i) {
      int row = i * 8 + wv * 2 + (lane >> 5);   // 0..63
      int c4 = lane & 31;
      int pc4 = c4 ^ ((row >> 2) & 3);          // inverse swizzle
      float4 v = *(const float4*)&fs[row * 128 + (pc4 << 2)];
      *(float4*)&ob[(size_t)(h * 64 + row) * L_LEN + (c4 << 2)] = v;
    }
  }
}

extern "C" void kernel_launch(void* const* d_in, const int* in_sizes, int n_in,
                              void* d_out, int out_size, void* d_ws, size_t ws_size,
                              hipStream_t stream) {
  const float* x    = (const float*)d_in[0];
  const float* dw_w = (const float*)d_in[1];
  const float* dw_b = (const float*)d_in[2];
  const float* ln_g = (const float*)d_in[3];
  const float* ln_b = (const float*)d_in[4];
  const float* off_w = (const float*)d_in[5];
  const float* off_b = (const float*)d_in[6];
  const float* dc_w = (const float*)d_in[7];
  float* out = (float*)d_out;

  char* ws = (char*)d_ws;
  short* Wp2 = (short*)ws;                 // 98,304 B
  uint2* g_pk = (uint2*)(ws + 0x20000);    // 3 MB packed exchange

  hipLaunchKernelGGL(repack_w2, dim3(192), dim3(256), 0, stream, dc_w, Wp2);
  hipLaunchKernelGGL(fused_deform, dim3(L_LEN / 128, B_N), dim3(256), 0, stream,
                     x, dw_w, dw_b, ln_g, ln_b, off_w, off_b, Wp2, g_pk, out);
}

// Round 9
// 183.168 us; speedup vs baseline: 1.0418x; 1.0418x over previous
//
#include <hip/hip_runtime.h>
#include <hip/hip_bf16.h>
#include <cstdint>
#include <cstddef>

#define C_CH 128
#define L_LEN 16384
#define B_N 8
#define K_T 3
#define EPS 1e-5f
#define WPADL 8
#define WIN 144   // staged rows: l = l0-8 .. l0+135 (verified R5/R6 window)

typedef __attribute__((ext_vector_type(8))) short short8;
typedef __attribute__((ext_vector_type(4))) float float4v;

__device__ __forceinline__ short f2bf(float f) {
  union { float f; unsigned u; } v; v.f = f;
  unsigned r = v.u + 0x7fffu + ((v.u >> 16) & 1u);
  return (short)(r >> 16);
}
__device__ __forceinline__ float bflo(unsigned d) {
  union { unsigned u; float f; } v; v.u = d << 16; return v.f;
}
__device__ __forceinline__ float bfhi(unsigned d) {
  union { unsigned u; float f; } v; v.u = d & 0xffff0000u; return v.f;
}
__device__ __forceinline__ unsigned packbf(float a, float b) {
  unsigned ua = __float_as_uint(a) + 0x8000u;
  unsigned ub = __float_as_uint(b) + 0x8000u;
  return (ua >> 16) | (ub & 0xffff0000u);
}
__device__ __forceinline__ int clampL(int v) {
  return v < 0 ? 0 : (v > L_LEN - 1 ? L_LEN - 1 : v);
}

// ---- repack dc_w [m][c][kt] f32 -> Wp2 bf16, linear = ((ks*4+qk)*128 + m)*8 + j,
// A[m][k=ks*32+qk*8+j] = dcw[m][c][kt], c = qk*32 + (ks&3)*8 + j, kt = ks>>2.
__global__ void repack_w2(const float* __restrict__ dc_w, short* __restrict__ Wp2) {
  int tid = blockIdx.x * 256 + threadIdx.x;
  if (tid >= C_CH * C_CH * K_T) return;
  int j = tid & 7;
  int m = (tid >> 3) & 127;
  int qk = (tid >> 10) & 3;
  int ks = tid >> 12;
  int kt = ks >> 2, s = ks & 3;
  int c = qk * 32 + s * 8 + j;
  Wp2[tid] = f2bf(dc_w[(m * C_CH + c) * K_T + kt]);
}

// ---- Fused kernel = R6 verbatim, plus three bounded tweaks:
//  (1) uint2-packed (wab, r01) exchange (verified in R8): full-line stores, 6 loads;
//  (2) s_setprio(1) around the MFMA kt-loop (independent-block regime);
//  (3) phase-A global loads issued before swt staging (loads in flight earlier).
// Direct R6 epilogue stores (R8's LDS-transpose epilogue regressed; reverted).
// LDS = 36,864 (xs) + 4,096 (swt) = 40,960 B exactly -> 4 blocks/CU.
__global__ __launch_bounds__(256, 4) void fused_deform(
    const float* __restrict__ x,
    const float* __restrict__ dw_w, const float* __restrict__ dw_b,
    const float* __restrict__ ln_g, const float* __restrict__ ln_b,
    const float* __restrict__ off_w, const float* __restrict__ off_b,
    const short* __restrict__ Wp2,
    uint2* __restrict__ g_pk,
    float* __restrict__ out) {
  __shared__ short xs[WIN * 128];   // 36,864 B
  __shared__ float swt[1024];       // 4,096 B: dw_w[384] dw_b[128] ln_gb_packed[128] off_w[384]

  int t = threadIdx.x;
  int b = blockIdx.y;
  int l0 = blockIdx.x * 128;
  int wb0 = l0 - WPADL;
  const float* xb = x + (size_t)b * C_CH * L_LEN;
  char* xsb = (char*)xs;

  int lane = t & 63, wv = t >> 6;

  // ---- phase A (verbatim R6 body): stage x -> LDS bf16, XOR-16 swizzled rows.
  // Issued FIRST so the HBM loads are in flight before swt staging.
  {
    int cc = wv * 4 + (lane >> 4);    // chunk 0..15
    int lqi = lane & 15;
    #pragma unroll
    for (int i = 0; i < 3; ++i) {
      int lq = i * 16 + lqi;          // quad-row task; 36*4 = 144 rows exact
      if (lq < 36) {
        int bl = wb0 + lq * 4;
        float fv[8][4];
        if (bl >= 0 && bl + 3 <= L_LEN - 1) {
          #pragma unroll
          for (int j = 0; j < 8; ++j) {
            float4 f = *(const float4*)(xb + (size_t)(cc * 8 + j) * L_LEN + bl);
            fv[j][0] = f.x; fv[j][1] = f.y; fv[j][2] = f.z; fv[j][3] = f.w;
          }
        } else {
          #pragma unroll
          for (int j = 0; j < 8; ++j)
            #pragma unroll
            for (int k = 0; k < 4; ++k)
              fv[j][k] = xb[(size_t)(cc * 8 + j) * L_LEN + clampL(bl + k)];
        }
        #pragma unroll
        for (int k = 0; k < 4; ++k) {
          int rr = lq * 4 + k;
          uint4 q;
          q.x = packbf(fv[0][k], fv[1][k]);
          q.y = packbf(fv[2][k], fv[3][k]);
          q.z = packbf(fv[4][k], fv[5][k]);
          q.w = packbf(fv[6][k], fv[7][k]);
          *(uint4*)(xsb + rr * 256 + ((cc ^ (rr & 15)) << 4)) = q;
        }
      }
    }
  }

  // ---- swt staging (L2-hot, hides under phase-A HBM loads)
  for (int i = t; i < 1024; i += 256) {
    float v;
    if (i < 384) v = dw_w[i];
    else if (i < 512) v = dw_b[i - 384];
    else if (i < 640) v = __uint_as_float(packbf(ln_g[i - 512], ln_b[i - 512]));
    else v = off_w[i - 640];
    swt[i] = v;
  }
  __syncthreads();   // covers swt + xs staging

  // ---- phase B (verbatim R6 producer): dwconv + LN + ReLU + offset linear,
  // post-reject (wab, r01) written packed to the block-private global slice.
  #pragma unroll
  for (int it = 0; it < 2; ++it) {
    int l_loc = (t >> 2) + it * 64;
    int sub = t & 3;
    int lg = l0 + l_loc;
    float mL = (lg >= 1) ? 1.f : 0.f;
    float mR = (lg + 1 < L_LEN) ? 1.f : 0.f;
    int rm = l_loc + WPADL;

    float ys[32];
    float sum = 0.f, sumsq = 0.f;
    #pragma unroll
    for (int oct = 0; oct < 4; ++oct) {
      int ch = sub * 4 + oct;
      int r0 = rm - 1, r1 = rm, r2 = rm + 1;
      uint4 q0 = *(const uint4*)(xsb + r0 * 256 + ((ch ^ (r0 & 15)) << 4));
      uint4 q1 = *(const uint4*)(xsb + r1 * 256 + ((ch ^ (r1 & 15)) << 4));
      uint4 q2 = *(const uint4*)(xsb + r2 * 256 + ((ch ^ (r2 & 15)) << 4));
      const unsigned* u0 = (const unsigned*)&q0;
      const unsigned* u1 = (const unsigned*)&q1;
      const unsigned* u2 = (const unsigned*)&q2;
      #pragma unroll
      for (int j = 0; j < 4; ++j) {
        int c = ch * 8 + 2 * j;
        float y0 = swt[384 + c] + mL * bflo(u0[j]) * swt[3 * c]
                 + bflo(u1[j]) * swt[3 * c + 1] + mR * bflo(u2[j]) * swt[3 * c + 2];
        float y1 = swt[385 + c] + mL * bfhi(u0[j]) * swt[3 * c + 3]
                 + bfhi(u1[j]) * swt[3 * c + 4] + mR * bfhi(u2[j]) * swt[3 * c + 5];
        ys[oct * 8 + 2 * j] = y0;
        ys[oct * 8 + 2 * j + 1] = y1;
        sum += y0 + y1;
        sumsq += y0 * y0 + y1 * y1;
      }
    }
    sum += __shfl_xor(sum, 1, 64);     sum += __shfl_xor(sum, 2, 64);
    sumsq += __shfl_xor(sumsq, 1, 64); sumsq += __shfl_xor(sumsq, 2, 64);
    float mean = sum * (1.f / C_CH);
    float var = sumsq * (1.f / C_CH) - mean * mean;
    float rstd = rsqrtf(var + EPS);

    float o0 = 0.f, o1 = 0.f, o2 = 0.f;
    const unsigned* lngb = (const unsigned*)swt;
    #pragma unroll
    for (int li = 0; li < 32; ++li) {
      int c = sub * 32 + li;
      unsigned gb = lngb[512 + c];
      float yn = (ys[li] - mean) * rstd * bflo(gb) + bfhi(gb);
      float yr = yn > 0.f ? yn : 0.f;
      o0 += yr * swt[640 + c];
      o1 += yr * swt[768 + c];
      o2 += yr * swt[896 + c];
    }
    o0 += __shfl_xor(o0, 1, 64); o0 += __shfl_xor(o0, 2, 64);
    o1 += __shfl_xor(o1, 1, 64); o1 += __shfl_xor(o1, 2, 64);
    o2 += __shfl_xor(o2, 1, 64); o2 += __shfl_xor(o2, 2, 64);

    if (sub < 3) {
      float o = (sub == 0 ? o0 : (sub == 1 ? o1 : o2)) + off_b[sub];
      float pos = (float)(lg + sub - 1) + o;
      float p0f = floorf(pos);
      float fr = pos - p0f;
      int i0 = (int)p0f, i1 = i0 + 1;
      float wa = (i0 >= 0 && i0 < L_LEN) ? (1.f - fr) : 0.f;
      float wbv = (i1 >= 0 && i1 < L_LEN) ? fr : 0.f;
      int i0c = clampL(i0), i1c = clampL(i1);
      unsigned wab = packbf(wa, wbv);
      int r0 = i0c - wb0;
      int r1 = i1c - wb0;
      if ((unsigned)r0 >= WIN) { r0 = 0; wab &= 0xffff0000u; }
      if ((unsigned)r1 >= WIN) { r1 = 0; wab &= 0x0000ffffu; }
      size_t di = ((size_t)b * K_T + sub) * L_LEN + lg;
      g_pk[di] = make_uint2(wab, (unsigned)r0 | ((unsigned)r1 << 16));
    }
  }
  __syncthreads();   // drains global stores (vmcnt(0) before s_barrier);
                     // block-private slice, same CU/L2 -> loads below are L2-hits

  // ---- phase C (verbatim R6 consumer, packed exchange loads)
  int qk = lane >> 4, hrow = lane & 15;

  unsigned c_wab[K_T][2], c_r01[K_T][2];
  {
    const uint2* gp = g_pk + (size_t)b * K_T * L_LEN + l0;
    #pragma unroll
    for (int kt = 0; kt < 3; ++kt) {
      #pragma unroll
      for (int nt = 0; nt < 2; ++nt) {
        int n = wv * 32 + nt * 16 + hrow;
        uint2 w = gp[(size_t)kt * L_LEN + n];
        c_wab[kt][nt] = w.x;
        c_r01[kt][nt] = w.y;
      }
    }
  }

  float4v acc[8][2];
  #pragma unroll
  for (int i = 0; i < 8; ++i) {
    acc[i][0] = (float4v){0.f, 0.f, 0.f, 0.f};
    acc[i][1] = (float4v){0.f, 0.f, 0.f, 0.f};
  }
  const short* wpb = Wp2 + qk * 1024 + hrow * 8;

  __builtin_amdgcn_s_setprio(1);   // MFMA-dense region; resident blocks are desynced
  #pragma unroll
  for (int kt = 0; kt < 3; ++kt) {
    float wa[2], wbv[2];
    int b0[2], m0_[2], b1[2], m1_[2];
    #pragma unroll
    for (int nt = 0; nt < 2; ++nt) {
      unsigned wab = c_wab[kt][nt];
      wa[nt] = bflo(wab);
      wbv[nt] = bfhi(wab);
      unsigned r01 = c_r01[kt][nt];
      int r0 = r01 & 0xffff, r1 = r01 >> 16;
      b0[nt] = r0 * 256; m0_[nt] = r0 & 15;
      b1[nt] = r1 * 256; m1_[nt] = r1 & 15;
    }
    #pragma unroll
    for (int s = 0; s < 4; ++s) {
      int ks = kt * 4 + s;
      int ch = qk * 4 + s;
      short8 bfrag[2];
      #pragma unroll
      for (int nt = 0; nt < 2; ++nt) {
        uint4 q0 = *(const uint4*)(xsb + b0[nt] + ((ch ^ m0_[nt]) << 4));
        uint4 q1 = *(const uint4*)(xsb + b1[nt] + ((ch ^ m1_[nt]) << 4));
        const unsigned* q0u = (const unsigned*)&q0;
        const unsigned* q1u = (const unsigned*)&q1;
        union { unsigned u[4]; short8 s8; } bu;
        #pragma unroll
        for (int j = 0; j < 4; ++j) {
          float glo = wa[nt] * bflo(q0u[j]) + wbv[nt] * bflo(q1u[j]);
          float ghi = wa[nt] * bfhi(q0u[j]) + wbv[nt] * bfhi(q1u[j]);
          bu.u[j] = packbf(glo, ghi);
        }
        bfrag[nt] = bu.s8;
      }
      const short* wk = wpb + ks * 4096;
      #pragma unroll
      for (int mt = 0; mt < 8; ++mt) {
        short8 a = *(const short8*)(wk + mt * 128);
        acc[mt][0] = __builtin_amdgcn_mfma_f32_16x16x32_bf16(a, bfrag[0], acc[mt][0], 0, 0, 0);
        acc[mt][1] = __builtin_amdgcn_mfma_f32_16x16x32_bf16(a, bfrag[1], acc[mt][1], 0, 0, 0);
      }
    }
  }
  __builtin_amdgcn_s_setprio(0);

  // ---- epilogue (verbatim R6 direct stores)
  float* ob = out + (size_t)b * C_CH * L_LEN + l0;
  #pragma unroll
  for (int mt = 0; mt < 8; ++mt) {
    #pragma unroll
    for (int nt = 0; nt < 2; ++nt) {
      int col = wv * 32 + nt * 16 + hrow;
      #pragma unroll
      for (int r = 0; r < 4; ++r) {
        ob[(size_t)(mt * 16 + qk * 4 + r) * L_LEN + col] = acc[mt][nt][r];
      }
    }
  }
}

extern "C" void kernel_launch(void* const* d_in, const int* in_sizes, int n_in,
                              void* d_out, int out_size, void* d_ws, size_t ws_size,
                              hipStream_t stream) {
  const float* x    = (const float*)d_in[0];
  const float* dw_w = (const float*)d_in[1];
  const float* dw_b = (const float*)d_in[2];
  const float* ln_g = (const float*)d_in[3];
  const float* ln_b = (const float*)d_in[4];
  const float* off_w = (const float*)d_in[5];
  const float* off_b = (const float*)d_in[6];
  const float* dc_w = (const float*)d_in[7];
  float* out = (float*)d_out;

  char* ws = (char*)d_ws;
  short* Wp2 = (short*)ws;                 // 98,304 B
  uint2* g_pk = (uint2*)(ws + 0x20000);    // 3 MB packed exchange

  hipLaunchKernelGGL(repack_w2, dim3(192), dim3(256), 0, stream, dc_w, Wp2);
  hipLaunchKernelGGL(fused_deform, dim3(L_LEN / 128, B_N), dim3(256), 0, stream,
                     x, dw_w, dw_b, ln_g, ln_b, off_w, off_b, Wp2, g_pk, out);
}

// Round 10
// 182.631 us; speedup vs baseline: 1.0449x; 1.0029x over previous
//
#include <hip/hip_runtime.h>
#include <hip/hip_bf16.h>
#include <cstdint>
#include <cstddef>

#define C_CH 128
#define L_LEN 16384
#define B_N 8
#define K_T 3
#define EPS 1e-5f
#define WPADL 8
#define WIN 144   // staged rows: l = l0-8 .. l0+135 (verified R5/R6 window)

typedef __attribute__((ext_vector_type(8))) short short8;
typedef __attribute__((ext_vector_type(4))) float float4v;

__device__ __forceinline__ short f2bf(float f) {
  union { float f; unsigned u; } v; v.f = f;
  unsigned r = v.u + 0x7fffu + ((v.u >> 16) & 1u);
  return (short)(r >> 16);
}
__device__ __forceinline__ float bflo(unsigned d) {
  union { unsigned u; float f; } v; v.u = d << 16; return v.f;
}
__device__ __forceinline__ float bfhi(unsigned d) {
  union { unsigned u; float f; } v; v.u = d & 0xffff0000u; return v.f;
}
__device__ __forceinline__ unsigned packbf(float a, float b) {
  unsigned ua = __float_as_uint(a) + 0x8000u;
  unsigned ub = __float_as_uint(b) + 0x8000u;
  return (ua >> 16) | (ub & 0xffff0000u);
}
__device__ __forceinline__ int clampL(int v) {
  return v < 0 ? 0 : (v > L_LEN - 1 ? L_LEN - 1 : v);
}

// ---- repack dc_w [m][c][kt] f32 -> Wp2 bf16, linear = ((ks*4+qk)*128 + m)*8 + j,
// A[m][k=ks*32+qk*8+j] = dcw[m][c][kt], c = qk*32 + (ks&3)*8 + j, kt = ks>>2.
__global__ void repack_w2(const float* __restrict__ dc_w, short* __restrict__ Wp2) {
  int tid = blockIdx.x * 256 + threadIdx.x;
  if (tid >= C_CH * C_CH * K_T) return;
  int j = tid & 7;
  int m = (tid >> 3) & 127;
  int qk = (tid >> 10) & 3;
  int ks = tid >> 12;
  int kt = ks >> 2, s = ks & 3;
  int c = qk * 32 + s * 8 + j;
  Wp2[tid] = f2bf(dc_w[(m * C_CH + c) * K_T + kt]);
}

// ---- Fused kernel = R6 verbatim (phases A, B, exchange arrays, mapping) with ONE
// change: phase C runs as two nt-passes (all kt,s for nt=0, store those 32 cols,
// then nt=1). Per-output MFMA order unchanged -> bit-identical numerics. The
// nt=0 store drain overlaps nt=1 compute; live accumulator halves (32 AGPR).
// LDS = 36,864 (xs) + 4,096 (swt) = 40,960 B exactly -> 4 blocks/CU.
__global__ __launch_bounds__(256, 4) void fused_deform(
    const float* __restrict__ x,
    const float* __restrict__ dw_w, const float* __restrict__ dw_b,
    const float* __restrict__ ln_g, const float* __restrict__ ln_b,
    const float* __restrict__ off_w, const float* __restrict__ off_b,
    const short* __restrict__ Wp2,
    unsigned* __restrict__ g_wab, unsigned* __restrict__ g_idx,
    float* __restrict__ out) {
  __shared__ short xs[WIN * 128];   // 36,864 B
  __shared__ float swt[1024];       // 4,096 B: dw_w[384] dw_b[128] ln_gb_packed[128] off_w[384]

  int t = threadIdx.x;
  int b = blockIdx.y;
  int l0 = blockIdx.x * 128;
  int wb0 = l0 - WPADL;
  const float* xb = x + (size_t)b * C_CH * L_LEN;
  char* xsb = (char*)xs;

  for (int i = t; i < 1024; i += 256) {
    float v;
    if (i < 384) v = dw_w[i];
    else if (i < 512) v = dw_b[i - 384];
    else if (i < 640) v = __uint_as_float(packbf(ln_g[i - 512], ln_b[i - 512]));
    else v = off_w[i - 640];
    swt[i] = v;
  }

  int lane = t & 63, wv = t >> 6;

  // ---- phase A (verbatim R6): stage x -> LDS bf16, XOR-16 swizzled rows.
  {
    int cc = wv * 4 + (lane >> 4);    // chunk 0..15
    int lqi = lane & 15;
    #pragma unroll
    for (int i = 0; i < 3; ++i) {
      int lq = i * 16 + lqi;          // quad-row task; 36*4 = 144 rows exact
      if (lq < 36) {
        int bl = wb0 + lq * 4;
        float fv[8][4];
        if (bl >= 0 && bl + 3 <= L_LEN - 1) {
          #pragma unroll
          for (int j = 0; j < 8; ++j) {
            float4 f = *(const float4*)(xb + (size_t)(cc * 8 + j) * L_LEN + bl);
            fv[j][0] = f.x; fv[j][1] = f.y; fv[j][2] = f.z; fv[j][3] = f.w;
          }
        } else {
          #pragma unroll
          for (int j = 0; j < 8; ++j)
            #pragma unroll
            for (int k = 0; k < 4; ++k)
              fv[j][k] = xb[(size_t)(cc * 8 + j) * L_LEN + clampL(bl + k)];
        }
        #pragma unroll
        for (int k = 0; k < 4; ++k) {
          int rr = lq * 4 + k;
          uint4 q;
          q.x = packbf(fv[0][k], fv[1][k]);
          q.y = packbf(fv[2][k], fv[3][k]);
          q.z = packbf(fv[4][k], fv[5][k]);
          q.w = packbf(fv[6][k], fv[7][k]);
          *(uint4*)(xsb + rr * 256 + ((cc ^ (rr & 15)) << 4)) = q;
        }
      }
    }
  }
  __syncthreads();   // covers swt + xs staging

  // ---- phase B (verbatim R6 producer): dwconv + LN + ReLU + offset linear,
  // post-reject (wab, r01) written to the block-private global slice.
  #pragma unroll
  for (int it = 0; it < 2; ++it) {
    int l_loc = (t >> 2) + it * 64;
    int sub = t & 3;
    int lg = l0 + l_loc;
    float mL = (lg >= 1) ? 1.f : 0.f;
    float mR = (lg + 1 < L_LEN) ? 1.f : 0.f;
    int rm = l_loc + WPADL;

    float ys[32];
    float sum = 0.f, sumsq = 0.f;
    #pragma unroll
    for (int oct = 0; oct < 4; ++oct) {
      int ch = sub * 4 + oct;
      int r0 = rm - 1, r1 = rm, r2 = rm + 1;
      uint4 q0 = *(const uint4*)(xsb + r0 * 256 + ((ch ^ (r0 & 15)) << 4));
      uint4 q1 = *(const uint4*)(xsb + r1 * 256 + ((ch ^ (r1 & 15)) << 4));
      uint4 q2 = *(const uint4*)(xsb + r2 * 256 + ((ch ^ (r2 & 15)) << 4));
      const unsigned* u0 = (const unsigned*)&q0;
      const unsigned* u1 = (const unsigned*)&q1;
      const unsigned* u2 = (const unsigned*)&q2;
      #pragma unroll
      for (int j = 0; j < 4; ++j) {
        int c = ch * 8 + 2 * j;
        float y0 = swt[384 + c] + mL * bflo(u0[j]) * swt[3 * c]
                 + bflo(u1[j]) * swt[3 * c + 1] + mR * bflo(u2[j]) * swt[3 * c + 2];
        float y1 = swt[385 + c] + mL * bfhi(u0[j]) * swt[3 * c + 3]
                 + bfhi(u1[j]) * swt[3 * c + 4] + mR * bfhi(u2[j]) * swt[3 * c + 5];
        ys[oct * 8 + 2 * j] = y0;
        ys[oct * 8 + 2 * j + 1] = y1;
        sum += y0 + y1;
        sumsq += y0 * y0 + y1 * y1;
      }
    }
    sum += __shfl_xor(sum, 1, 64);     sum += __shfl_xor(sum, 2, 64);
    sumsq += __shfl_xor(sumsq, 1, 64); sumsq += __shfl_xor(sumsq, 2, 64);
    float mean = sum * (1.f / C_CH);
    float var = sumsq * (1.f / C_CH) - mean * mean;
    float rstd = rsqrtf(var + EPS);

    float o0 = 0.f, o1 = 0.f, o2 = 0.f;
    const unsigned* lngb = (const unsigned*)swt;
    #pragma unroll
    for (int li = 0; li < 32; ++li) {
      int c = sub * 32 + li;
      unsigned gb = lngb[512 + c];
      float yn = (ys[li] - mean) * rstd * bflo(gb) + bfhi(gb);
      float yr = yn > 0.f ? yn : 0.f;
      o0 += yr * swt[640 + c];
      o1 += yr * swt[768 + c];
      o2 += yr * swt[896 + c];
    }
    o0 += __shfl_xor(o0, 1, 64); o0 += __shfl_xor(o0, 2, 64);
    o1 += __shfl_xor(o1, 1, 64); o1 += __shfl_xor(o1, 2, 64);
    o2 += __shfl_xor(o2, 1, 64); o2 += __shfl_xor(o2, 2, 64);

    if (sub < 3) {
      float o = (sub == 0 ? o0 : (sub == 1 ? o1 : o2)) + off_b[sub];
      float pos = (float)(lg + sub - 1) + o;
      float p0f = floorf(pos);
      float fr = pos - p0f;
      int i0 = (int)p0f, i1 = i0 + 1;
      float wa = (i0 >= 0 && i0 < L_LEN) ? (1.f - fr) : 0.f;
      float wbv = (i1 >= 0 && i1 < L_LEN) ? fr : 0.f;
      int i0c = clampL(i0), i1c = clampL(i1);
      unsigned wab = packbf(wa, wbv);
      int r0 = i0c - wb0;
      int r1 = i1c - wb0;
      if ((unsigned)r0 >= WIN) { r0 = 0; wab &= 0xffff0000u; }
      if ((unsigned)r1 >= WIN) { r1 = 0; wab &= 0x0000ffffu; }
      size_t di = ((size_t)b * K_T + sub) * L_LEN + lg;
      g_wab[di] = wab;
      g_idx[di] = (unsigned)r0 | ((unsigned)r1 << 16);
    }
  }
  __syncthreads();   // drains global stores (vmcnt(0) before s_barrier);
                     // block-private slice, same CU/L2 -> loads below are L2-hits

  // ---- phase C: R6 consumer, restructured into two nt-passes.
  int qk = lane >> 4, hrow = lane & 15;

  unsigned c_wab[K_T][2], c_r01[K_T][2];
  {
    const unsigned* gw = g_wab + (size_t)b * K_T * L_LEN + l0;
    const unsigned* gi = g_idx + (size_t)b * K_T * L_LEN + l0;
    #pragma unroll
    for (int kt = 0; kt < 3; ++kt) {
      #pragma unroll
      for (int nt = 0; nt < 2; ++nt) {
        int n = wv * 32 + nt * 16 + hrow;
        c_wab[kt][nt] = gw[(size_t)kt * L_LEN + n];
        c_r01[kt][nt] = gi[(size_t)kt * L_LEN + n];
      }
    }
  }

  const short* wpb = Wp2 + qk * 1024 + hrow * 8;
  float* ob = out + (size_t)b * C_CH * L_LEN + l0;

  #pragma unroll
  for (int nt = 0; nt < 2; ++nt) {
    float4v acc[8];
    #pragma unroll
    for (int i = 0; i < 8; ++i) acc[i] = (float4v){0.f, 0.f, 0.f, 0.f};

    #pragma unroll
    for (int kt = 0; kt < 3; ++kt) {
      unsigned wab = c_wab[kt][nt];
      float wa = bflo(wab);
      float wbv = bfhi(wab);
      unsigned r01 = c_r01[kt][nt];
      int r0 = r01 & 0xffff, r1 = r01 >> 16;
      int b0 = r0 * 256, m0_ = r0 & 15;
      int b1 = r1 * 256, m1_ = r1 & 15;
      #pragma unroll
      for (int s = 0; s < 4; ++s) {
        int ks = kt * 4 + s;
        int ch = qk * 4 + s;
        uint4 q0 = *(const uint4*)(xsb + b0 + ((ch ^ m0_) << 4));
        uint4 q1 = *(const uint4*)(xsb + b1 + ((ch ^ m1_) << 4));
        const unsigned* q0u = (const unsigned*)&q0;
        const unsigned* q1u = (const unsigned*)&q1;
        union { unsigned u[4]; short8 s8; } bu;
        #pragma unroll
        for (int j = 0; j < 4; ++j) {
          float glo = wa * bflo(q0u[j]) + wbv * bflo(q1u[j]);
          float ghi = wa * bfhi(q0u[j]) + wbv * bfhi(q1u[j]);
          bu.u[j] = packbf(glo, ghi);
        }
        short8 bfrag = bu.s8;
        const short* wk = wpb + ks * 4096;
        #pragma unroll
        for (int mt = 0; mt < 8; ++mt) {
          short8 a = *(const short8*)(wk + mt * 128);
          acc[mt] = __builtin_amdgcn_mfma_f32_16x16x32_bf16(a, bfrag, acc[mt], 0, 0, 0);
        }
      }
    }

    // store this 32-col half now; drain overlaps the other pass's compute
    int col = wv * 32 + nt * 16 + hrow;
    #pragma unroll
    for (int mt = 0; mt < 8; ++mt) {
      #pragma unroll
      for (int r = 0; r < 4; ++r) {
        ob[(size_t)(mt * 16 + qk * 4 + r) * L_LEN + col] = acc[mt][r];
      }
    }
  }
}

extern "C" void kernel_launch(void* const* d_in, const int* in_sizes, int n_in,
                              void* d_out, int out_size, void* d_ws, size_t ws_size,
                              hipStream_t stream) {
  const float* x    = (const float*)d_in[0];
  const float* dw_w = (const float*)d_in[1];
  const float* dw_b = (const float*)d_in[2];
  const float* ln_g = (const float*)d_in[3];
  const float* ln_b = (const float*)d_in[4];
  const float* off_w = (const float*)d_in[5];
  const float* off_b = (const float*)d_in[6];
  const float* dc_w = (const float*)d_in[7];
  float* out = (float*)d_out;

  char* ws = (char*)d_ws;
  short* Wp2 = (short*)ws;                        // 98,304 B
  unsigned* g_wab = (unsigned*)(ws + 0x20000);    // 1.5 MB
  unsigned* g_idx = (unsigned*)(ws + 0x1A0000);   // 1.5 MB

  hipLaunchKernelGGL(repack_w2, dim3(192), dim3(256), 0, stream, dc_w, Wp2);
  hipLaunchKernelGGL(fused_deform, dim3(L_LEN / 128, B_N), dim3(256), 0, stream,
                     x, dw_w, dw_b, ln_g, ln_b, off_w, off_b, Wp2, g_wab, g_idx, out);
}